// Round 1
// 266.147 us; speedup vs baseline: 1.0420x; 1.0420x over previous
//
#include <hip/hip_runtime.h>

typedef unsigned short u16;
typedef unsigned int u32;

typedef __bf16 bf16x8 __attribute__((ext_vector_type(8)));
typedef float f32x4 __attribute__((ext_vector_type(4)));

__device__ __forceinline__ u16 f2bf(float f) {
  u32 u = __float_as_uint(f);
  u = u + 0x7fffu + ((u >> 16) & 1u);
  return (u16)(u >> 16);
}
__device__ __forceinline__ float bf2f(u16 u) {
  return __uint_as_float(((u32)u) << 16);
}

// strict-< insertion keeps earliest index on ties (matches jax.lax.top_k)
__device__ __forceinline__ void ins3(float d, int s,
                                     float& d0, float& d1, float& d2,
                                     int& i0, int& i1, int& i2) {
  if (d < d2) {
    if (d < d1) {
      d2 = d1; i2 = i1;
      if (d < d0) { d1 = d0; i1 = i0; d0 = d; i0 = s; }
      else        { d1 = d; i1 = s; }
    } else { d2 = d; i2 = s; }
  }
}

// branchless strict-< top-3 insert: 3 cmp + 10 cndmask
__device__ __forceinline__ void ins3b(float d, int s,
                                      float& d0, float& d1, float& d2,
                                      int& i0, int& i1, int& i2) {
  bool c2 = d < d2, c1 = d < d1, c0 = d < d0;
  d2 = c1 ? d1 : (c2 ? d : d2);
  i2 = c1 ? i1 : (c2 ? s : i2);
  d1 = c0 ? d0 : (c1 ? d : d1);
  i1 = c0 ? i0 : (c1 ? s : i1);
  d0 = c0 ? d : d0;
  i0 = c0 ? s : i0;
}

// ---------------------------------------------------------------- weights -> bf16 in MFMA-fragment order + zero BN stat accumulators
// W1f layout: [kt=12][g=16][lane=64][e=8] : element = W1[g*16 + (l&15)][kt*32 + (l>>4)*8 + e]
// W2f layout: [kt= 8][g= 8][lane=64][e=8] : element = W2[g*16 + (l&15)][kt*32 + (l>>4)*8 + e]
__global__ __launch_bounds__(256) void conv_w_kernel(
    const float* __restrict__ W1, const float* __restrict__ W2,
    u16* __restrict__ W1f, u16* __restrict__ W2f, float* __restrict__ stats) {
  int i = blockIdx.x * 256 + threadIdx.x;      // 512 blocks * 256 = 131072 exactly
  if (i < 98304) {
    int e = i & 7, l = (i >> 3) & 63, g = (i >> 9) & 15, kt = i >> 13;
    int col = g * 16 + (l & 15);
    int k = kt * 32 + (l >> 4) * 8 + e;
    W1f[i] = f2bf(W1[col * 384 + k]);
  } else {
    int j = i - 98304;                         // 0..32767
    int e = j & 7, l = (j >> 3) & 63, g = (j >> 9) & 7, kt = j >> 12;
    int col = g * 16 + (l & 15);
    int k = kt * 32 + (l >> 4) * 8 + e;
    W2f[j] = f2bf(W2[col * 256 + k]);
  }
  if (i < 768) stats[i] = 0.f;                 // gs1[256] gq1[256] gs2[128] gq2[128]
}

// ---------------------------------------------------------------- 3NN: indices + weights per point
// Block: 256 threads = 32 target points x 8 sub-scans of 128 sources.
// Each sub-scan runs two independent 64-source streams (short cmp->cndmask
// chains); contiguous ascending split keeps index-order tie-break exact.
// Grid 2048 -> ~7 blocks/CU (vs 4 before) for latency hiding.
__global__ __launch_bounds__(256) void knn_kernel(
    const float* __restrict__ txyz, const float* __restrict__ sxyz,
    float4* __restrict__ nn) {
  __shared__ float4 sP[1032];      // padded: index s + (s>>7) -> 8 sub-chunks on disjoint banks
  __shared__ float  md[32 * 24];
  __shared__ int    mi[32 * 24];

  const int t = threadIdx.x;
  const int b = blockIdx.x >> 7;
  const int n0 = (blockIdx.x & 127) << 5;

  const float* sb = sxyz + (size_t)b * 1024 * 3;
  for (int i = t; i < 1024; i += 256) {
    float x = sb[i * 3 + 0], y = sb[i * 3 + 1], z = sb[i * 3 + 2];
    float r2 = __fadd_rn(__fadd_rn(__fmul_rn(x, x), __fmul_rn(y, y)), __fmul_rn(z, z));
    sP[i + (i >> 7)] = make_float4(x, y, z, r2);
  }
  __syncthreads();

  const int p = t >> 3, sub = t & 7;
  const int n = n0 + p;
  const float* tb = txyz + ((size_t)b * 4096 + n) * 3;
  const float t0 = tb[0], t1 = tb[1], t2 = tb[2];
  const float q2 = __fadd_rn(__fadd_rn(__fmul_rn(t0, t0), __fmul_rn(t1, t1)), __fmul_rn(t2, t2));

  float d0a = 1e30f, d1a = 1e30f, d2a = 1e30f;
  int   i0a = 0, i1a = 0, i2a = 0;
  float d0b = 1e30f, d1b = 1e30f, d2b = 1e30f;
  int   i0b = 0, i1b = 0, i2b = 0;
  const int sbeg = sub * 128;

#pragma unroll 4
  for (int off = 0; off < 64; ++off) {
    const int sa = sbeg + off;
    const int sb2 = sbeg + 64 + off;
    float4 pa = sP[sa + (sa >> 7)];
    float4 pb = sP[sb2 + (sb2 >> 7)];

    float ca = __fmul_rn(t0, pa.x);
    ca = __fadd_rn(ca, __fmul_rn(t1, pa.y));
    ca = __fadd_rn(ca, __fmul_rn(t2, pa.z));
    float da = __fadd_rn(__fadd_rn(q2, pa.w), __fmul_rn(-2.0f, ca));
    da = fmaxf(da, 0.0f);

    float cb = __fmul_rn(t0, pb.x);
    cb = __fadd_rn(cb, __fmul_rn(t1, pb.y));
    cb = __fadd_rn(cb, __fmul_rn(t2, pb.z));
    float db = __fadd_rn(__fadd_rn(q2, pb.w), __fmul_rn(-2.0f, cb));
    db = fmaxf(db, 0.0f);

    ins3b(da, sa, d0a, d1a, d2a, i0a, i1a, i2a);
    ins3b(db, sb2, d0b, d1b, d2b, i0b, i1b, i2b);
  }
  // merge stream b into a: all b indices > all a indices, strict-< preserves tie-break
  ins3(d0b, i0b, d0a, d1a, d2a, i0a, i1a, i2a);
  ins3(d1b, i1b, d0a, d1a, d2a, i0a, i1a, i2a);
  ins3(d2b, i2b, d0a, d1a, d2a, i0a, i1a, i2a);

  md[p * 24 + sub * 3 + 0] = d0a; md[p * 24 + sub * 3 + 1] = d1a; md[p * 24 + sub * 3 + 2] = d2a;
  mi[p * 24 + sub * 3 + 0] = i0a; mi[p * 24 + sub * 3 + 1] = i1a; mi[p * 24 + sub * 3 + 2] = i2a;
  __syncthreads();

  if (sub == 0) {
    float D0 = 1e30f, D1 = 1e30f, D2 = 1e30f;
    int I0 = 0, I1 = 0, I2 = 0;
    for (int ss = 0; ss < 8; ++ss)          // ascending chunk => earliest index wins ties
      for (int k = 0; k < 3; ++k)
        ins3(md[p * 24 + ss * 3 + k], mi[p * 24 + ss * 3 + k], D0, D1, D2, I0, I1, I2);
    int idxs[3] = {I0, I1, I2};
    float w[3], wsum = 0.f;
    for (int k = 0; k < 3; ++k) {
      float4 sp = sP[idxs[k] + (idxs[k] >> 7)];
      float dx = t0 - sp.x, dy = t1 - sp.y, dz = t2 - sp.z;
      float dd = __fadd_rn(__fadd_rn(__fmul_rn(dx, dx), __fmul_rn(dy, dy)), __fmul_rn(dz, dz));
      w[k] = 1.0f / (dd + 1e-8f);
      wsum += w[k];
    }
    float inv = 1.0f / wsum;
    size_t pt = (size_t)b * 4096 + n;
    nn[pt * 2 + 0] = make_float4(__int_as_float(I0), __int_as_float(I1), __int_as_float(I2), 0.f);
    nn[pt * 2 + 1] = make_float4(w[0] * inv, w[1] * inv, w[2] * inv, 0.f);
  }
}

// ---------------------------------------------------------------- fused gather+concat+GEMM1
// Block = 128 points x full 256 output cols; 512 threads (8 waves, 2x4).
// Phase 1: build the full A tile (128 x 384 bf16) in LDS from L2-resident
//          sfeat gathers + skip (kills the Xb HBM round-trip entirely).
// Phase 2: barrier-free K-loop: A frags from LDS, B frags as coalesced 16B/lane
//          loads from the pre-permuted W1f (L2-hot, 196KB).
// XCD swizzle: 64 consecutive logical blocks per XCD -> 2 batches (2MB sfeat) per XCD L2.
__global__ __launch_bounds__(512) void gemm1f_kernel(
    const float4* __restrict__ nn, const float* __restrict__ sfeat,
    const float* __restrict__ skip, const u16* __restrict__ W1f,
    u16* __restrict__ Y, float* __restrict__ gs, float* __restrict__ gq) {
  __shared__ u16 As[128 * 392];            // pad 384->392: frag reads spread across banks
  __shared__ float csum[256], csq[256];

  const int t = threadIdx.x;
  const int raw = blockIdx.x;
  const int logical = (raw & 7) * 64 + (raw >> 3);   // bijective, 512 = 8*64
  const int b = logical >> 5;              // batch 0..15
  const int pg = logical & 31;             // point-group of 128
  const size_t n0 = (size_t)b * 4096 + (size_t)pg * 128;

  // ---- phase 1: stage A (4 threads per row; 16B LDS stores)
  {
    const int r = t >> 2, p = t & 3;
    const size_t n = n0 + r;
    float4 nni = nn[n * 2 + 0];
    float4 nnw = nn[n * 2 + 1];
    const int j0 = __float_as_int(nni.x), j1 = __float_as_int(nni.y), j2 = __float_as_int(nni.z);
    const float w0 = nnw.x, w1 = nnw.y, w2 = nnw.z;
    const float4* fb = (const float4*)(sfeat + (size_t)b * 1024 * 256);
    const float4* f0 = fb + (size_t)j0 * 64;
    const float4* f1 = fb + (size_t)j1 * 64;
    const float4* f2 = fb + (size_t)j2 * 64;
    u16* dst = As + r * 392;
#pragma unroll
    for (int v = 0; v < 8; ++v) {
      const int c4 = p * 16 + 2 * v;
      float4 a0 = f0[c4], a1 = f0[c4 + 1];
      float4 b0 = f1[c4], b1 = f1[c4 + 1];
      float4 c0 = f2[c4], c1 = f2[c4 + 1];
      union { uint4 u; u16 s[8]; } o;
      o.s[0] = f2bf(w0 * a0.x + w1 * b0.x + w2 * c0.x);
      o.s[1] = f2bf(w0 * a0.y + w1 * b0.y + w2 * c0.y);
      o.s[2] = f2bf(w0 * a0.z + w1 * b0.z + w2 * c0.z);
      o.s[3] = f2bf(w0 * a0.w + w1 * b0.w + w2 * c0.w);
      o.s[4] = f2bf(w0 * a1.x + w1 * b1.x + w2 * c1.x);
      o.s[5] = f2bf(w0 * a1.y + w1 * b1.y + w2 * c1.y);
      o.s[6] = f2bf(w0 * a1.z + w1 * b1.z + w2 * c1.z);
      o.s[7] = f2bf(w0 * a1.w + w1 * b1.w + w2 * c1.w);
      *(uint4*)(dst + p * 64 + v * 8) = o.u;
    }
    const float4* sk = (const float4*)(skip + n * 128);
#pragma unroll
    for (int v = 0; v < 4; ++v) {
      const int c4 = p * 8 + 2 * v;
      float4 s0 = sk[c4], s1 = sk[c4 + 1];
      union { uint4 u; u16 s[8]; } o;
      o.s[0] = f2bf(s0.x); o.s[1] = f2bf(s0.y); o.s[2] = f2bf(s0.z); o.s[3] = f2bf(s0.w);
      o.s[4] = f2bf(s1.x); o.s[5] = f2bf(s1.y); o.s[6] = f2bf(s1.z); o.s[7] = f2bf(s1.w);
      *(uint4*)(dst + 256 + p * 32 + v * 8) = o.u;
    }
  }
  if (t < 256) { csum[t] = 0.f; csq[t] = 0.f; }
  __syncthreads();

  // ---- phase 2: barrier-free K-loop
  const int w = t >> 6, l = t & 63;
  const int wm = w >> 2, wn = w & 3;       // wave grid 2x4: 64 rows x 64 cols each
  const int lm = l & 15, q = l >> 4;

  f32x4 acc[4][4] = {};
  const u16* Bf = W1f + (wn * 4) * 512 + l * 8;    // (kt*16+g)*512 + l*8

#pragma unroll 4
  for (int kt = 0; kt < 12; ++kt) {
    bf16x8 af[4], bfv[4];
#pragma unroll
    for (int j = 0; j < 4; ++j)
      bfv[j] = *(const bf16x8*)(Bf + kt * 8192 + j * 512);
#pragma unroll
    for (int i = 0; i < 4; ++i)
      af[i] = *(const bf16x8*)&As[(wm * 64 + i * 16 + lm) * 392 + kt * 32 + q * 8];
#pragma unroll
    for (int i = 0; i < 4; ++i)
#pragma unroll
      for (int j = 0; j < 4; ++j)
        acc[i][j] = __builtin_amdgcn_mfma_f32_16x16x32_bf16(af[i], bfv[j], acc[i][j], 0, 0, 0);
  }

  // ---- epilogue: bf16 Y1 + column stats
  float lsum[4] = {0, 0, 0, 0}, lsq[4] = {0, 0, 0, 0};
  const int colb = wn * 64;
#pragma unroll
  for (int i = 0; i < 4; ++i) {
    const size_t mg = n0 + wm * 64 + i * 16 + q * 4;
#pragma unroll
    for (int r = 0; r < 4; ++r) {
      const size_t ro = (mg + r) * 256;
#pragma unroll
      for (int j = 0; j < 4; ++j) {
        float v = acc[i][j][r];
        Y[ro + colb + j * 16 + lm] = f2bf(v);
        lsum[j] += v; lsq[j] += v * v;
      }
    }
  }
#pragma unroll
  for (int j = 0; j < 4; ++j) {
    atomicAdd(&csum[colb + j * 16 + lm], lsum[j]);
    atomicAdd(&csq[colb + j * 16 + lm], lsq[j]);
  }
  __syncthreads();
  if (t < 256) {
    atomicAdd(&gs[t], csum[t]);
    atomicAdd(&gq[t], csq[t]);
  }
}

// ---------------------------------------------------------------- BN finalize (trivial): a=gamma*rsqrt(var+eps), b=beta-mean*a
__global__ void bn_finalize_kernel(const float* __restrict__ stats,
                                   const float* __restrict__ gamma, const float* __restrict__ beta,
                                   float* __restrict__ ab, int C, float invN) {
  int c = threadIdx.x;
  if (c >= C) return;
  float mean = stats[c] * invN;
  float var = stats[C + c] * invN - mean * mean;
  float a = gamma[c] * rsqrtf(var + 1e-5f);
  ab[c] = a;
  ab[C + c] = beta[c] - mean * a;
}

__device__ __forceinline__ uint4 bnrelu_pack(uint4 raw, const float* a1s, const float* b1s, int kb) {
  union { uint4 v; u16 s[8]; } u;
  u.v = raw;
#pragma unroll
  for (int e = 0; e < 8; ++e) {
    float f = fmaxf(bf2f(u.s[e]) * a1s[kb + e] + b1s[kb + e], 0.f);
    u.s[e] = f2bf(f);
  }
  return u.v;
}

// ---------------------------------------------------------------- GEMM2: out = relu(bn1(Y1)) * W2^T
// Same one-shot A staging (bn1+relu fused into the stage) + barrier-free K-loop
// with fragment-ordered W2f from L2. 256 threads, wave grid 2x2.
__global__ __launch_bounds__(256) void gemm2f_kernel(
    const u16* __restrict__ Yin, const u16* __restrict__ W2f,
    const float* __restrict__ ab1, float* __restrict__ out,
    float* __restrict__ gs, float* __restrict__ gq) {
  __shared__ u16 As[128 * 264];            // pad 256->264
  __shared__ float a1s[256], b1s[256];
  __shared__ float csum[128], csq[128];

  const int t = threadIdx.x;
  const int bm = blockIdx.x;
  a1s[t] = ab1[t];
  b1s[t] = ab1[256 + t];
  if (t < 128) { csum[t] = 0.f; csq[t] = 0.f; }
  __syncthreads();

  // ---- stage A with fused bn1+relu (2 threads per row, 16B stores)
  {
    const int r = t >> 1, h = t & 1;
    const u16* Ag = Yin + (size_t)(bm * 128 + r) * 256 + h * 128;
    u16* dst = As + r * 264 + h * 128;
#pragma unroll
    for (int v = 0; v < 16; ++v) {
      uint4 rawv = *(const uint4*)(Ag + v * 8);
      rawv = bnrelu_pack(rawv, a1s, b1s, h * 128 + v * 8);
      *(uint4*)(dst + v * 8) = rawv;
    }
  }
  __syncthreads();

  const int w = t >> 6, l = t & 63;
  const int wm = w >> 1, wn = w & 1;       // wave grid 2x2: 64 rows x 64 cols each
  const int lm = l & 15, q = l >> 4;

  f32x4 acc[4][4] = {};
  const u16* Bf = W2f + (wn * 4) * 512 + l * 8;    // (kt*8+g)*512 + l*8

#pragma unroll 4
  for (int kt = 0; kt < 8; ++kt) {
    bf16x8 af[4], bfv[4];
#pragma unroll
    for (int j = 0; j < 4; ++j)
      bfv[j] = *(const bf16x8*)(Bf + kt * 4096 + j * 512);
#pragma unroll
    for (int i = 0; i < 4; ++i)
      af[i] = *(const bf16x8*)&As[(wm * 64 + i * 16 + lm) * 264 + kt * 32 + q * 8];
#pragma unroll
    for (int i = 0; i < 4; ++i)
#pragma unroll
      for (int j = 0; j < 4; ++j)
        acc[i][j] = __builtin_amdgcn_mfma_f32_16x16x32_bf16(af[i], bfv[j], acc[i][j], 0, 0, 0);
  }

  float lsum[4] = {0, 0, 0, 0}, lsq[4] = {0, 0, 0, 0};
  const int colb = wn * 64;
#pragma unroll
  for (int i = 0; i < 4; ++i) {
    const int mg = bm * 128 + wm * 64 + i * 16 + q * 4;
#pragma unroll
    for (int r = 0; r < 4; ++r) {
      const size_t ro = (size_t)(mg + r) * 128;
#pragma unroll
      for (int j = 0; j < 4; ++j) {
        float v = acc[i][j][r];
        out[ro + colb + j * 16 + lm] = v;
        lsum[j] += v; lsq[j] += v * v;
      }
    }
  }
#pragma unroll
  for (int j = 0; j < 4; ++j) {
    atomicAdd(&csum[colb + j * 16 + lm], lsum[j]);
    atomicAdd(&csq[colb + j * 16 + lm], lsq[j]);
  }
  __syncthreads();
  if (t < 128) {
    atomicAdd(&gs[t], csum[t]);
    atomicAdd(&gq[t], csq[t]);
  }
}

// ---------------------------------------------------------------- final BN2+ReLU in place on d_out
__global__ __launch_bounds__(256) void bn_relu_out_kernel(float* __restrict__ out,
                                                          const float* __restrict__ ab2) {
  int idx = blockIdx.x * 256 + threadIdx.x;   // 8192*256 = 2097152 = exactly out_size/4
  float4* o4 = (float4*)out;
  float4 v = o4[idx];
  int c = (idx * 4) & 127;
  v.x = fmaxf(v.x * ab2[c + 0] + ab2[128 + c + 0], 0.f);
  v.y = fmaxf(v.y * ab2[c + 1] + ab2[128 + c + 1], 0.f);
  v.z = fmaxf(v.z * ab2[c + 2] + ab2[128 + c + 2], 0.f);
  v.w = fmaxf(v.w * ab2[c + 3] + ab2[128 + c + 3], 0.f);
  o4[idx] = v;
}

extern "C" void kernel_launch(void* const* d_in, const int* in_sizes, int n_in,
                              void* d_out, int out_size, void* d_ws, size_t ws_size,
                              hipStream_t stream) {
  const float* txyz  = (const float*)d_in[0];
  const float* sxyz  = (const float*)d_in[1];
  const float* sfeat = (const float*)d_in[2];
  const float* skip  = (const float*)d_in[3];
  const float* W1    = (const float*)d_in[4];
  const float* g1    = (const float*)d_in[5];
  const float* be1   = (const float*)d_in[6];
  const float* W2    = (const float*)d_in[7];
  const float* g2    = (const float*)d_in[8];
  const float* be2   = (const float*)d_in[9];
  float* out = (float*)d_out;

  char* ws = (char*)d_ws;
  u16*    Y1  = (u16*)(ws + 0ull);                // 65536*256*2 = 33554432
  float4* nnd = (float4*)(ws + 33554432ull);      // 65536*32   =  2097152
  u16*    W1f = (u16*)(ws + 35651584ull);         // 196608
  u16*    W2f = (u16*)(ws + 35848192ull);         // 65536
  float*  stats = (float*)(ws + 35913728ull);     // 768*4: gs1[256] gq1[256] gs2[128] gq2[128]
  float*  ab1 = (float*)(ws + 35916800ull);       // 512*4
  float*  ab2 = (float*)(ws + 35918848ull);       // 256*4

  conv_w_kernel<<<512, 256, 0, stream>>>(W1, W2, W1f, W2f, stats);
  knn_kernel<<<2048, 256, 0, stream>>>(txyz, sxyz, nnd);
  gemm1f_kernel<<<512, 512, 0, stream>>>(nnd, sfeat, skip, W1f, Y1, stats, stats + 256);
  bn_finalize_kernel<<<1, 256, 0, stream>>>(stats, g1, be1, ab1, 256, 1.0f / 65536.0f);
  gemm2f_kernel<<<512, 256, 0, stream>>>(Y1, W2f, ab1, out, stats + 512, stats + 640);
  bn_finalize_kernel<<<1, 128, 0, stream>>>(stats + 512, g2, be2, ab2, 128, 1.0f / 65536.0f);
  bn_relu_out_kernel<<<8192, 256, 0, stream>>>(out, ab2);
}